// Round 11
// baseline (736.185 us; speedup 1.0000x reference)
//
#include <hip/hip_runtime.h>
#include <hip/hip_bf16.h>
#include <math.h>

#define U_N   8192
#define I_N   16384
#define D_N   64
#define OUT_N 64
#define BN    32           // items per iteration tile
#define BM    128          // users per block (4 waves x 2 groups x 16)
#define NCH   8            // item chunks -> 512 blocks = 2/CU, all resident
#define ITERS 64           // (I_N/NCH)/BN
#define VN_ST 72           // Vn stride (halves): 144B rows
#define VT_ST 40           // Vt stride (halves): 80B rows, b128-aligned

typedef _Float16 half8  __attribute__((ext_vector_type(8)));
typedef short    bf16x8 __attribute__((ext_vector_type(8)));
typedef short    bf16x4 __attribute__((ext_vector_type(4)));
typedef float    f32x4  __attribute__((ext_vector_type(4)));
typedef int      int4v  __attribute__((ext_vector_type(4)));

static __device__ __forceinline__ unsigned short f2bf(float f) {
    union { __hip_bfloat16 h; unsigned short u; } cv;
    cv.h = __float2bfloat16(f);
    return cv.u;
}
static __device__ __forceinline__ float fast_exp2(float x) {
#if __has_builtin(__builtin_amdgcn_exp2f)
    return __builtin_amdgcn_exp2f(x);
#else
    return __expf(x * 0.6931471805599453f);
#endif
}
// pack 4 fp32 -> bf16x4 by truncation (v_perm high-16s)
static __device__ __forceinline__ bf16x4 pack4(float a, float b, float c2, float d) {
    union { unsigned u[2]; bf16x4 h; } x;
#if __has_builtin(__builtin_amdgcn_perm)
    x.u[0] = __builtin_amdgcn_perm(__float_as_uint(b), __float_as_uint(a), 0x07060302u);
    x.u[1] = __builtin_amdgcn_perm(__float_as_uint(d), __float_as_uint(c2), 0x07060302u);
#else
    x.u[0] = (__float_as_uint(b) & 0xffff0000u) | (__float_as_uint(a) >> 16);
    x.u[1] = (__float_as_uint(d) & 0xffff0000u) | (__float_as_uint(c2) >> 16);
#endif
    return x.h;
}
// LDS-only barrier: global prefetches stay in flight across it.
static __device__ __forceinline__ void bar() {
    asm volatile("s_waitcnt lgkmcnt(0)\n\ts_barrier" ::: "memory");
}
// PV matmul 16x16x16 bf16: A-operand layout == S^T C-layout (r9-verified).
static __device__ __forceinline__ f32x4 pv_mfma(bf16x4 a, bf16x4 b, f32x4 c) {
#if __has_builtin(__builtin_amdgcn_mfma_f32_16x16x16bf16_1k)
    return __builtin_amdgcn_mfma_f32_16x16x16bf16_1k(a, b, c, 0, 0, 0);
#else
    f32x4 d;
    asm volatile("v_mfma_f32_16x16x16_bf16 %0, %1, %2, %3"
                 : "=v"(d) : "v"(a), "v"(b), "v"(c));
    return d;
#endif
}

// ---------------------------------------------------------------------------
// prep_items, re-gridded: one thread per (item, 16-dim group) -> 256 blocks
// (r10 had 64 blocks = 0.25/CU, latency-bound). itemH f16 [item][dim];
// itemTt bf16 tiled transpose with interleaved slot order (one b128 per
// (row,q) yields both PV K-group fragments).
// ---------------------------------------------------------------------------
__global__ __launch_bounds__(256)
void prep_items(const float* __restrict__ item,
                _Float16* __restrict__ itemH,
                unsigned short* __restrict__ itemTt)
{
    const int tid = blockIdx.x * 256 + threadIdx.x;    // I_N*4 threads
    const int i   = tid >> 2;                           // item
    const int g   = tid & 3;                            // 16-dim group
    const float* src = item + (size_t)i * D_N + g * 16;
    f32x4 v0 = *(const f32x4*)(src);
    f32x4 v1 = *(const f32x4*)(src + 4);
    f32x4 v2 = *(const f32x4*)(src + 8);
    f32x4 v3 = *(const f32x4*)(src + 12);

    half8 h0, h1;
    #pragma unroll
    for (int k = 0; k < 4; ++k) {
        h0[k] = (_Float16)v0[k]; h0[4 + k] = (_Float16)v1[k];
        h1[k] = (_Float16)v2[k]; h1[4 + k] = (_Float16)v3[k];
    }
    *(half8*)&itemH[(size_t)i * D_N + g * 16]     = h0;
    *(half8*)&itemH[(size_t)i * D_N + g * 16 + 8] = h1;

    const int il    = i & 31;
    const int islot = 8 * ((il & 15) >> 2) + ((il >> 4) << 2) + (il & 3);
    unsigned short* dst = itemTt + (size_t)(i >> 5) * (D_N * 32) + (size_t)(g * 16) * 32 + islot;
    #pragma unroll
    for (int k = 0; k < 4; ++k) {
        dst[(4 * 0 + k) * 32] = f2bf(v0[k]);
        dst[(4 * 1 + k) * 32] = f2bf(v1[k]);
        dst[(4 * 2 + k) * 32] = f2bf(v2[k]);
        dst[(4 * 3 + k) * 32] = f2bf(v3[k]);
    }
}

// ---------------------------------------------------------------------------
// Named-register pipeline state (arrays/structs/lambdas demote to scratch;
// r3/r4 lesson). Two user groups share one staged tile.
// ---------------------------------------------------------------------------
#define DECL_SET(S) \
    int4v adj##S##a0, adj##S##b0, adj##S##a1, adj##S##b1; \
    half8 vn##S; bf16x8 vt##S;

#define LOAD_ADJ(S, tidx) do { \
    const size_t o_ = (size_t)(tidx) * BN; \
    adj##S##a0 = *(const int4v*)&adjq0[o_];      \
    adj##S##b0 = *(const int4v*)&adjq0[o_ + 16]; \
    adj##S##a1 = *(const int4v*)&adjq1[o_];      \
    adj##S##b1 = *(const int4v*)&adjq1[o_ + 16]; \
} while (0)

#define LOAD_TILE(S, tidx) do { \
    const size_t o_ = (size_t)(tidx) * BN; \
    vn##S = *(const half8*)&itemH[(ibase0 + o_ + (t >> 3)) * D_N + (t & 7) * 8]; \
    vt##S = *(const bf16x8*)&itemTt[((ibase0 + o_) >> 5) * (D_N * 32) \
                                    + (size_t)(t >> 2) * 32 + (t & 3) * 8]; \
} while (0)

#define COMMIT(S, bufw) do { \
    *(half8*)&Vn[bufw][(t >> 3) * VN_ST + (t & 7) * 8] = vn##S; \
    *(bf16x8*)&Vt[bufw][(t >> 2) * VT_ST + (t & 3) * 8] = vt##S; \
} while (0)

// S^T = Item * User^T (f16, ufrag pre-scaled by log2e -> log2-domain scores).
// Lane (q,c): T0/T2[r] = items 4q+r, T1/T3[r] = items 16+4q+r; users
// urow0+c (group 0) and urow0+64+c (group 1). The two groups' chains are
// independent -> they fill each other's pipeline bubbles. LDS reads shared.
#define COMPUTE_REST(S, bufr) do { \
    half8 a00 = *(const half8*)&Vn[bufr][(c)      * VN_ST      + q * 8]; \
    half8 a01 = *(const half8*)&Vn[bufr][(c)      * VN_ST + 32 + q * 8]; \
    half8 a10 = *(const half8*)&Vn[bufr][(16 + c) * VN_ST      + q * 8]; \
    half8 a11 = *(const half8*)&Vn[bufr][(16 + c) * VN_ST + 32 + q * 8]; \
    bf16x8 w0 = *(const bf16x8*)&Vt[bufr][(c)      * VT_ST + 8 * q]; \
    bf16x8 w1 = *(const bf16x8*)&Vt[bufr][(16 + c) * VT_ST + 8 * q]; \
    bf16x8 w2 = *(const bf16x8*)&Vt[bufr][(32 + c) * VT_ST + 8 * q]; \
    bf16x8 w3 = *(const bf16x8*)&Vt[bufr][(48 + c) * VT_ST + 8 * q]; \
    f32x4 T0 = (f32x4){0.f,0.f,0.f,0.f}; \
    f32x4 T1 = T0, T2 = T0, T3 = T0; \
    T0 = __builtin_amdgcn_mfma_f32_16x16x32_f16(a00, ufrag0, T0, 0, 0, 0); \
    T2 = __builtin_amdgcn_mfma_f32_16x16x32_f16(a00, ufrag2, T2, 0, 0, 0); \
    T0 = __builtin_amdgcn_mfma_f32_16x16x32_f16(a01, ufrag1, T0, 0, 0, 0); \
    T2 = __builtin_amdgcn_mfma_f32_16x16x32_f16(a01, ufrag3, T2, 0, 0, 0); \
    T1 = __builtin_amdgcn_mfma_f32_16x16x32_f16(a10, ufrag0, T1, 0, 0, 0); \
    T3 = __builtin_amdgcn_mfma_f32_16x16x32_f16(a10, ufrag2, T3, 0, 0, 0); \
    T1 = __builtin_amdgcn_mfma_f32_16x16x32_f16(a11, ufrag1, T1, 0, 0, 0); \
    T3 = __builtin_amdgcn_mfma_f32_16x16x32_f16(a11, ufrag3, T3, 0, 0, 0); \
    const float e0_ = fast_exp2((adj##S##a0[0] != 0) ? T0[0] : 0.0f); \
    const float e1_ = fast_exp2((adj##S##a0[1] != 0) ? T0[1] : 0.0f); \
    const float e2_ = fast_exp2((adj##S##a0[2] != 0) ? T0[2] : 0.0f); \
    const float e3_ = fast_exp2((adj##S##a0[3] != 0) ? T0[3] : 0.0f); \
    const float f0_ = fast_exp2((adj##S##b0[0] != 0) ? T1[0] : 0.0f); \
    const float f1_ = fast_exp2((adj##S##b0[1] != 0) ? T1[1] : 0.0f); \
    const float f2_ = fast_exp2((adj##S##b0[2] != 0) ? T1[2] : 0.0f); \
    const float f3_ = fast_exp2((adj##S##b0[3] != 0) ? T1[3] : 0.0f); \
    const float g0_ = fast_exp2((adj##S##a1[0] != 0) ? T2[0] : 0.0f); \
    const float g1_ = fast_exp2((adj##S##a1[1] != 0) ? T2[1] : 0.0f); \
    const float g2_ = fast_exp2((adj##S##a1[2] != 0) ? T2[2] : 0.0f); \
    const float g3_ = fast_exp2((adj##S##a1[3] != 0) ? T2[3] : 0.0f); \
    const float h0_ = fast_exp2((adj##S##b1[0] != 0) ? T3[0] : 0.0f); \
    const float h1_ = fast_exp2((adj##S##b1[1] != 0) ? T3[1] : 0.0f); \
    const float h2_ = fast_exp2((adj##S##b1[2] != 0) ? T3[2] : 0.0f); \
    const float h3_ = fast_exp2((adj##S##b1[3] != 0) ? T3[3] : 0.0f); \
    lc0 += ((e0_ + e1_) + (e2_ + e3_)) + ((f0_ + f1_) + (f2_ + f3_)); \
    lc1 += ((g0_ + g1_) + (g2_ + g3_)) + ((h0_ + h1_) + (h2_ + h3_)); \
    bf16x4 p0 = pack4(e0_, e1_, e2_, e3_); \
    bf16x4 p1 = pack4(f0_, f1_, f2_, f3_); \
    bf16x4 p2 = pack4(g0_, g1_, g2_, g3_); \
    bf16x4 p3 = pack4(h0_, h1_, h2_, h3_); \
    bf16x4 lo0 = __builtin_shufflevector(w0, w0, 0, 1, 2, 3); \
    bf16x4 hi0 = __builtin_shufflevector(w0, w0, 4, 5, 6, 7); \
    bf16x4 lo1 = __builtin_shufflevector(w1, w1, 0, 1, 2, 3); \
    bf16x4 hi1 = __builtin_shufflevector(w1, w1, 4, 5, 6, 7); \
    bf16x4 lo2 = __builtin_shufflevector(w2, w2, 0, 1, 2, 3); \
    bf16x4 hi2 = __builtin_shufflevector(w2, w2, 4, 5, 6, 7); \
    bf16x4 lo3 = __builtin_shufflevector(w3, w3, 0, 1, 2, 3); \
    bf16x4 hi3 = __builtin_shufflevector(w3, w3, 4, 5, 6, 7); \
    O0 = pv_mfma(p0, lo0, O0);  O4 = pv_mfma(p2, lo0, O4); \
    O0 = pv_mfma(p1, hi0, O0);  O4 = pv_mfma(p3, hi0, O4); \
    O1 = pv_mfma(p0, lo1, O1);  O5 = pv_mfma(p2, lo1, O5); \
    O1 = pv_mfma(p1, hi1, O1);  O5 = pv_mfma(p3, hi1, O5); \
    O2 = pv_mfma(p0, lo2, O2);  O6 = pv_mfma(p2, lo2, O6); \
    O2 = pv_mfma(p1, hi2, O2);  O6 = pv_mfma(p3, hi2, O6); \
    O3 = pv_mfma(p0, lo3, O3);  O7 = pv_mfma(p2, lo3, O7); \
    O3 = pv_mfma(p1, hi3, O3);  O7 = pv_mfma(p3, hi3, O7); \
} while (0)

// ---------------------------------------------------------------------------
// Main: ping-pong LDS tiles, LDS-only barriers, transposed-S, direct-reg PV,
// TWO user groups per wave sharing each staged tile (BM=128).
// ---------------------------------------------------------------------------
__global__ __launch_bounds__(256, 3)
void atten_main(const float* __restrict__ user_emb,
                const _Float16* __restrict__ itemH,
                const unsigned short* __restrict__ itemTt,
                const int*   __restrict__ adj,
                float* __restrict__ wsO,
                float* __restrict__ wsL)
{
    __shared__ _Float16 Vn[2][BN * VN_ST];
    __shared__ short    Vt[2][D_N * VT_ST];

    const int ch   = blockIdx.x;
    const int ub   = blockIdx.y;
    const int t    = threadIdx.x;
    const int w    = t >> 6;
    const int lane = t & 63;
    const int c    = lane & 15;
    const int q    = lane >> 4;

    const int    urow0  = ub * BM + w * 16;    // group 0 rows; group 1 = +64
    const size_t ibase0 = (size_t)ch * (I_N / NCH);

    // user fragments pre-scaled by log2(e); groups 0 and 1
    half8 ufrag0, ufrag1, ufrag2, ufrag3;
    {
        const float s = 1.44269504088896f;
        const float* up0 = user_emb + (size_t)(urow0 + c) * D_N + q * 8;
        const float* up1 = up0 + (size_t)64 * D_N;
        f32x4 a0 = *(const f32x4*)(up0);
        f32x4 b0 = *(const f32x4*)(up0 + 4);
        f32x4 a1 = *(const f32x4*)(up0 + 32);
        f32x4 b1 = *(const f32x4*)(up0 + 36);
        f32x4 a2 = *(const f32x4*)(up1);
        f32x4 b2 = *(const f32x4*)(up1 + 4);
        f32x4 a3 = *(const f32x4*)(up1 + 32);
        f32x4 b3 = *(const f32x4*)(up1 + 36);
        #pragma unroll
        for (int j = 0; j < 4; ++j) {
            ufrag0[j] = (_Float16)(a0[j] * s); ufrag0[4 + j] = (_Float16)(b0[j] * s);
            ufrag1[j] = (_Float16)(a1[j] * s); ufrag1[4 + j] = (_Float16)(b1[j] * s);
            ufrag2[j] = (_Float16)(a2[j] * s); ufrag2[4 + j] = (_Float16)(b2[j] * s);
            ufrag3[j] = (_Float16)(a3[j] * s); ufrag3[4 + j] = (_Float16)(b3[j] * s);
        }
    }

    f32x4 O0 = (f32x4){0.f,0.f,0.f,0.f};
    f32x4 O1 = O0, O2 = O0, O3 = O0, O4 = O0, O5 = O0, O6 = O0, O7 = O0;
    float lc0 = 0.f, lc1 = 0.f;

    const int* adjq0 = adj + (size_t)(urow0 + c) * I_N + ibase0 + 4 * q;
    const int* adjq1 = adjq0 + (size_t)64 * I_N;

    DECL_SET(A)
    DECL_SET(B)

    LOAD_TILE(A, 0); LOAD_ADJ(A, 0);
    LOAD_TILE(B, 1); LOAD_ADJ(B, 1);
    COMMIT(A, 0);
    LOAD_TILE(A, 2);
    bar();

    for (int k = 0; k < ITERS; k += 2) {
        {   // iter k: consume buf0 + adjA; commit B; reload tileB, adjA
            COMMIT(B, 1);
            LOAD_TILE(B, (k + 3 < ITERS) ? k + 3 : ITERS - 1);
            COMPUTE_REST(A, 0);
            LOAD_ADJ(A, (k + 2 < ITERS) ? k + 2 : ITERS - 1);
            bar();
        }
        {   // iter k+1: consume buf1 + adjB; commit A; reload tileA, adjB
            COMMIT(A, 0);
            LOAD_TILE(A, (k + 4 < ITERS) ? k + 4 : ITERS - 1);
            COMPUTE_REST(B, 1);
            LOAD_ADJ(B, (k + 3 < ITERS) ? k + 3 : ITERS - 1);
            bar();
        }
    }

    // l: lanes c, c+16, c+32, c+48 hold partials for each user
    lc0 += __shfl_xor(lc0, 16);
    lc0 += __shfl_xor(lc0, 32);
    lc1 += __shfl_xor(lc1, 16);
    lc1 += __shfl_xor(lc1, 32);

    // chunk partials, both groups
    {
        float* d0 = wsO + ((size_t)ch * U_N + urow0 + 4 * q + 0) * D_N;
        float* d1 = wsO + ((size_t)ch * U_N + urow0 + 4 * q + 1) * D_N;
        float* d2 = wsO + ((size_t)ch * U_N + urow0 + 4 * q + 2) * D_N;
        float* d3 = wsO + ((size_t)ch * U_N + urow0 + 4 * q + 3) * D_N;
        d0[c] = O0[0]; d0[16 + c] = O1[0]; d0[32 + c] = O2[0]; d0[48 + c] = O3[0];
        d1[c] = O0[1]; d1[16 + c] = O1[1]; d1[32 + c] = O2[1]; d1[48 + c] = O3[1];
        d2[c] = O0[2]; d2[16 + c] = O1[2]; d2[32 + c] = O2[2]; d2[48 + c] = O3[2];
        d3[c] = O0[3]; d3[16 + c] = O1[3]; d3[32 + c] = O2[3]; d3[48 + c] = O3[3];
        float* e0 = d0 + (size_t)64 * D_N;
        float* e1 = d1 + (size_t)64 * D_N;
        float* e2 = d2 + (size_t)64 * D_N;
        float* e3 = d3 + (size_t)64 * D_N;
        e0[c] = O4[0]; e0[16 + c] = O5[0]; e0[32 + c] = O6[0]; e0[48 + c] = O7[0];
        e1[c] = O4[1]; e1[16 + c] = O5[1]; e1[32 + c] = O6[1]; e1[48 + c] = O7[1];
        e2[c] = O4[2]; e2[16 + c] = O5[2]; e2[32 + c] = O6[2]; e2[48 + c] = O7[2];
        e3[c] = O4[3]; e3[16 + c] = O5[3]; e3[32 + c] = O6[3]; e3[48 + c] = O7[3];
    }
    if (q == 0) {
        wsL[(size_t)ch * U_N + urow0 + c]      = lc0;
        wsL[(size_t)ch * U_N + urow0 + 64 + c] = lc1;
    }
}

// ---------------------------------------------------------------------------
// Combine: sum chunk partials, normalize, project by attention_weight.
// ---------------------------------------------------------------------------
__global__ __launch_bounds__(256)
void atten_combine(const float* __restrict__ wsO,
                   const float* __restrict__ wsL,
                   const float* __restrict__ attw,
                   float* __restrict__ out,
                   int nch)
{
    __shared__ float inv[64];
    __shared__ float agg[64][68];
    __shared__ float Wl[64][68];

    const int t  = threadIdx.x;
    const int u0 = blockIdx.x * 64;

    {
        const int d = t >> 2, o0 = (t & 3) * 16;
        const float* src = attw + d * OUT_N + o0;
        #pragma unroll
        for (int j = 0; j < 4; ++j)
            *(f32x4*)&Wl[d][o0 + 4 * j] = *(const f32x4*)(src + 4 * j);
    }
    if (t < 64) {
        float L = 0.f;
        for (int cc = 0; cc < nch; ++cc) L += wsL[(size_t)cc * U_N + u0 + t];
        inv[t] = 1.0f / L;
    }
    __syncthreads();

    {
        const int ul = t >> 2, d0 = (t & 3) * 16;
        const int u = u0 + ul;
        f32x4 a4[4];
        #pragma unroll
        for (int j = 0; j < 4; ++j) a4[j] = (f32x4){0.f, 0.f, 0.f, 0.f};
        for (int cc = 0; cc < nch; ++cc) {
            const float* src = wsO + ((size_t)cc * U_N + u) * D_N + d0;
            #pragma unroll
            for (int j = 0; j < 4; ++j) a4[j] += *(const f32x4*)(src + 4 * j);
        }
        const float s = inv[ul];
        #pragma unroll
        for (int j = 0; j < 4; ++j)
            *(f32x4*)&agg[ul][d0 + 4 * j] = a4[j] * s;
    }
    __syncthreads();

    {
        const int ul = t >> 2, o0 = (t & 3) * 16;
        f32x4 acc[4];
        #pragma unroll
        for (int j = 0; j < 4; ++j) acc[j] = (f32x4){0.f, 0.f, 0.f, 0.f};
        for (int d = 0; d < 64; ++d) {
            const float av = agg[ul][d];
            #pragma unroll
            for (int j = 0; j < 4; ++j) {
                f32x4 wv = *(const f32x4*)&Wl[d][o0 + 4 * j];
                acc[j] += wv * av;
            }
        }
        float* dst = out + (size_t)(u0 + ul) * OUT_N + o0;
        #pragma unroll
        for (int j = 0; j < 4; ++j)
            *(f32x4*)(dst + 4 * j) = acc[j];
    }
}

// ---------------------------------------------------------------------------
extern "C" void kernel_launch(void* const* d_in, const int* in_sizes, int n_in,
                              void* d_out, int out_size, void* d_ws, size_t ws_size,
                              hipStream_t stream)
{
    const float* user_emb = (const float*)d_in[0];
    const float* item_emb = (const float*)d_in[1];
    const float* attw     = (const float*)d_in[2];
    const int*   adj      = (const int*)d_in[3];
    float* out = (float*)d_out;

    // ws layout: wsO | wsL | itemH | itemTt
    float*          wsO    = (float*)d_ws;
    float*          wsL    = wsO + (size_t)NCH * U_N * D_N;
    _Float16*       itemH  = (_Float16*)(wsL + (size_t)NCH * U_N);
    unsigned short* itemTt = (unsigned short*)(itemH + (size_t)I_N * D_N);

    prep_items<<<dim3(I_N * 4 / 256), 256, 0, stream>>>(item_emb, itemH, itemTt);
    atten_main<<<dim3(NCH, U_N / BM), 256, 0, stream>>>(user_emb, itemH, itemTt, adj,
                                                        wsO, wsL);
    atten_combine<<<dim3(U_N / 64), 256, 0, stream>>>(wsO, wsL, attw, out, NCH);
}